// Round 1
// baseline (331.880 us; speedup 1.0000x reference)
//
#include <hip/hip_runtime.h>
#include <hip/hip_bf16.h>
#include <math.h>

#define BATCH_N 8
#define SEQ_T   2048
#define DIM_D   1024
#define HS_N    128

using bf16x8_t = __attribute__((ext_vector_type(8))) __bf16;
using bf16x4_t = __attribute__((ext_vector_type(4))) __bf16;
using f32x4_t  = __attribute__((ext_vector_type(4))) float;

__device__ __forceinline__ f32x4_t mfma_16x16x32(bf16x8_t a, bf16x8_t b, f32x4_t c) {
  return __builtin_amdgcn_mfma_f32_16x16x32_bf16(a, b, c, 0, 0, 0);
}

// ---------------------------------------------------------------------------
// Kernel 0: cast W -> bf16, rows [K:0-127][Q:128-255][V:256-383], Q pre-scaled
// ---------------------------------------------------------------------------
__global__ __launch_bounds__(256) void castw_kernel(
    const float* __restrict__ Wk, const float* __restrict__ Wq,
    const float* __restrict__ Wv, __bf16* __restrict__ Wb) {
  int idx = blockIdx.x * 256 + threadIdx.x;   // 98304 threads, 4 elems each
  int e   = idx * 4;
  int row = e >> 10;
  int col = e & 1023;
  const float* src;
  float sc = 1.0f;
  if (row < 128) {
    src = Wk + row * DIM_D + col;
  } else if (row < 256) {
    src = Wq + (row - 128) * DIM_D + col;
    sc  = 0.08838834764831845f;  // 1/sqrt(HS) folded into Wq
  } else {
    src = Wv + (row - 256) * DIM_D + col;
  }
  float4 v = *(const float4*)src;
  bf16x4_t o;
  o[0] = (__bf16)(v.x * sc); o[1] = (__bf16)(v.y * sc);
  o[2] = (__bf16)(v.z * sc); o[3] = (__bf16)(v.w * sc);
  *(bf16x4_t*)(Wb + e) = o;
}

// ---------------------------------------------------------------------------
// Kernel 1: projections. Block = 64 m-rows x 384 n-cols, 4 waves.
// Wave w: n in [w*96, w*96+96) = 6 n-tiles; 4 m-tiles of 16.
// A frag: m = lane&15, k = (lane>>4)*8 + j  (contiguous in x row-major)
// B frag: n = lane&15, k = (lane>>4)*8 + j  (contiguous in Wb row-major)
// D tile: col = lane&15, row = (lane>>4)*4 + r
// Outputs: Qb,Kb [B,T,HS] bf16 ; Vt [B,HS,T] bf16 (transposed for PV B-frags)
// ---------------------------------------------------------------------------
__global__ __launch_bounds__(256) void proj_kernel(
    const float* __restrict__ x, const __bf16* __restrict__ Wb,
    __bf16* __restrict__ Qb, __bf16* __restrict__ Kb, __bf16* __restrict__ Vt) {
  const int lane = threadIdx.x & 63;
  const int wave = threadIdx.x >> 6;
  const int lr = lane & 15;
  const int lq = lane >> 4;
  const int m0 = blockIdx.x * 64;

  f32x4_t acc[4][6];
  #pragma unroll
  for (int mt = 0; mt < 4; ++mt)
    #pragma unroll
    for (int nt = 0; nt < 6; ++nt) acc[mt][nt] = (f32x4_t){0.f, 0.f, 0.f, 0.f};

  const float*  xb = x  + (size_t)(m0 + lr) * DIM_D + lq * 8;
  const __bf16* wb = Wb + (size_t)(wave * 96 + lr) * DIM_D + lq * 8;

  for (int ks = 0; ks < 32; ++ks) {
    const int k0 = ks * 32;
    bf16x8_t af[4];
    #pragma unroll
    for (int mt = 0; mt < 4; ++mt) {
      const float* p = xb + mt * 16 * DIM_D + k0;
      float4 f0 = *(const float4*)p;
      float4 f1 = *(const float4*)(p + 4);
      bf16x8_t a;
      a[0] = (__bf16)f0.x; a[1] = (__bf16)f0.y;
      a[2] = (__bf16)f0.z; a[3] = (__bf16)f0.w;
      a[4] = (__bf16)f1.x; a[5] = (__bf16)f1.y;
      a[6] = (__bf16)f1.z; a[7] = (__bf16)f1.w;
      af[mt] = a;
    }
    bf16x8_t bfr[6];
    #pragma unroll
    for (int nt = 0; nt < 6; ++nt)
      bfr[nt] = *(const bf16x8_t*)(wb + nt * 16 * DIM_D + k0);
    #pragma unroll
    for (int mt = 0; mt < 4; ++mt)
      #pragma unroll
      for (int nt = 0; nt < 6; ++nt)
        acc[mt][nt] = mfma_16x16x32(af[mt], bfr[nt], acc[mt][nt]);
  }

  #pragma unroll
  for (int mt = 0; mt < 4; ++mt) {
    const int rowb = m0 + mt * 16 + lq * 4;  // D row = quad*4 + r
    #pragma unroll
    for (int nt = 0; nt < 6; ++nt) {
      const int nn = wave * 96 + nt * 16 + lr;  // D col = lane&15
      if (nn < 256) {
        __bf16* dst = (nn < 128) ? (Kb + nn) : (Qb + (nn - 128));
        #pragma unroll
        for (int r = 0; r < 4; ++r)
          dst[(size_t)(rowb + r) * HS_N] = (__bf16)acc[mt][nt][r];
      } else {
        const int bb = rowb >> 11;        // batch (tiles never straddle: 64|2048)
        const int t0 = rowb & 2047;       // 4-aligned -> packed 8B store
        bf16x4_t o;
        #pragma unroll
        for (int r = 0; r < 4; ++r) o[r] = (__bf16)acc[mt][nt][r];
        *(bf16x4_t*)(Vt + (size_t)bb * (HS_N * SEQ_T) + (size_t)(nn - 256) * SEQ_T + t0) = o;
      }
    }
  }
}

// ---------------------------------------------------------------------------
// Kernel 2: flash attention. 1 wave per block; wave handles q-tiles pj and
// 127-pj (constant total work ~2080 keys). K-tile = 64 keys.
// ---------------------------------------------------------------------------
__global__ __launch_bounds__(64) void attn_kernel(
    const __bf16* __restrict__ Qb, const __bf16* __restrict__ Kb,
    const __bf16* __restrict__ Vt, float* __restrict__ out) {
  __shared__ __bf16 pbuf[16 * 72];  // P round-trip C/D->A layout; stride 72 (2-way=free)
  const int lane = threadIdx.x;
  const int lr = lane & 15;
  const int lq = lane >> 4;
  const int b  = blockIdx.x >> 6;
  const int pj = blockIdx.x & 63;

  const __bf16* Qbb = Qb + (size_t)b * (SEQ_T * HS_N);
  const __bf16* Kbb = Kb + (size_t)b * (SEQ_T * HS_N);
  const __bf16* Vbb = Vt + (size_t)b * (HS_N * SEQ_T);
  float* ob = out + (size_t)b * (SEQ_T * HS_N);

  for (int half = 0; half < 2; ++half) {
    const int q0 = (half ? (127 - pj) : pj) * 16;

    bf16x8_t qf[4];
    #pragma unroll
    for (int ks = 0; ks < 4; ++ks)
      qf[ks] = *(const bf16x8_t*)(Qbb + (size_t)(q0 + lr) * HS_N + ks * 32 + lq * 8);

    f32x4_t Oa[8];
    #pragma unroll
    for (int o = 0; o < 8; ++o) Oa[o] = (f32x4_t){0.f, 0.f, 0.f, 0.f};
    float mrow[4] = {-INFINITY, -INFINITY, -INFINITY, -INFINITY};
    float lrow[4] = {0.f, 0.f, 0.f, 0.f};

    for (int kk = 0; kk < q0 + 16; kk += 64) {
      int nact = (q0 + 16 - kk) >> 4;
      if (nact > 4) nact = 4;

      // S = Qhat . K^T   (scale already folded into Q)
      f32x4_t s[4];
      #pragma unroll
      for (int nt = 0; nt < 4; ++nt) {
        f32x4_t sv = (f32x4_t){0.f, 0.f, 0.f, 0.f};
        if (nt < nact) {
          const __bf16* kp = Kbb + (size_t)(kk + nt * 16 + lr) * HS_N + lq * 8;
          #pragma unroll
          for (int ks = 0; ks < 4; ++ks)
            sv = mfma_16x16x32(qf[ks], *(const bf16x8_t*)(kp + ks * 32), sv);
          // causal mask: only bites on the diagonal tile (col>row impossible
          // for strictly-below tiles since tiles are 16-aligned)
          const int col = kk + nt * 16 + lr;
          #pragma unroll
          for (int r = 0; r < 4; ++r)
            if (col > q0 + lq * 4 + r) sv[r] = -INFINITY;
        }
        s[nt] = sv;
      }

      // online softmax: row spread across 16 lanes of the quad-group
      float alpha[4];
      #pragma unroll
      for (int r = 0; r < 4; ++r) {
        float mv = mrow[r];
        #pragma unroll
        for (int nt = 0; nt < 4; ++nt)
          if (nt < nact) mv = fmaxf(mv, s[nt][r]);
        mv = fmaxf(mv, __shfl_xor(mv, 1));
        mv = fmaxf(mv, __shfl_xor(mv, 2));
        mv = fmaxf(mv, __shfl_xor(mv, 4));
        mv = fmaxf(mv, __shfl_xor(mv, 8));
        alpha[r] = __expf(mrow[r] - mv);   // first iter: exp(-inf)=0
        mrow[r]  = mv;
      }

      float rs[4] = {0.f, 0.f, 0.f, 0.f};
      #pragma unroll
      for (int nt = 0; nt < 4; ++nt) {
        if (nt < nact) {
          #pragma unroll
          for (int r = 0; r < 4; ++r) {
            float p = __expf(s[nt][r] - mrow[r]);  // masked -> exp(-inf)=0
            s[nt][r] = p;
            rs[r] += p;
          }
        }
      }
      #pragma unroll
      for (int r = 0; r < 4; ++r) {
        rs[r] += __shfl_xor(rs[r], 1);
        rs[r] += __shfl_xor(rs[r], 2);
        rs[r] += __shfl_xor(rs[r], 4);
        rs[r] += __shfl_xor(rs[r], 8);
        lrow[r] = lrow[r] * alpha[r] + rs[r];
      }
      f32x4_t av = {alpha[0], alpha[1], alpha[2], alpha[3]};
      #pragma unroll
      for (int o = 0; o < 8; ++o) Oa[o] *= av;

      // P: C/D layout -> LDS -> A layout (zero-fill inactive tiles)
      #pragma unroll
      for (int nt = 0; nt < 4; ++nt) {
        #pragma unroll
        for (int r = 0; r < 4; ++r) {
          float pv = (nt < nact) ? s[nt][r] : 0.f;
          pbuf[(lq * 4 + r) * 72 + nt * 16 + lr] = (__bf16)pv;
        }
      }
      const int ksteps = (nact + 1) >> 1;
      #pragma unroll
      for (int k2 = 0; k2 < 2; ++k2) {
        if (k2 < ksteps) {
          bf16x8_t afr = *(const bf16x8_t*)(pbuf + lr * 72 + k2 * 32 + lq * 8);
          #pragma unroll
          for (int o = 0; o < 8; ++o) {
            bf16x8_t vf = *(const bf16x8_t*)(Vbb + (size_t)(o * 16 + lr) * SEQ_T
                                             + kk + k2 * 32 + lq * 8);
            Oa[o] = mfma_16x16x32(afr, vf, Oa[o]);
          }
        }
      }
    }

    #pragma unroll
    for (int r = 0; r < 4; ++r) {
      const float rl = 1.0f / lrow[r];
      const int rowg = q0 + lq * 4 + r;
      #pragma unroll
      for (int o = 0; o < 8; ++o)
        ob[(size_t)rowg * HS_N + o * 16 + lr] = Oa[o][r] * rl;
    }
  }
}

// ---------------------------------------------------------------------------
extern "C" void kernel_launch(void* const* d_in, const int* in_sizes, int n_in,
                              void* d_out, int out_size, void* d_ws, size_t ws_size,
                              hipStream_t stream) {
  const float* x  = (const float*)d_in[0];
  const float* Wk = (const float*)d_in[1];
  const float* Wq = (const float*)d_in[2];
  const float* Wv = (const float*)d_in[3];
  float* out = (float*)d_out;

  char* ws = (char*)d_ws;
  __bf16* Wb = (__bf16*)ws;                          //   786432 B
  __bf16* Qb = (__bf16*)(ws + 786432);               //  4194304 B
  __bf16* Kb = (__bf16*)(ws + 786432 + 4194304);     //  4194304 B
  __bf16* Vt = (__bf16*)(ws + 786432 + 8388608);     //  4194304 B  (total ~12.75 MB)

  castw_kernel<<<384, 256, 0, stream>>>(Wk, Wq, Wv, Wb);
  proj_kernel<<<BATCH_N * SEQ_T / 64, 256, 0, stream>>>(x, Wb, Qb, Kb, Vt);
  attn_kernel<<<BATCH_N * 64, 64, 0, stream>>>(Qb, Kb, Vt, out);
}

// Round 2
// 234.022 us; speedup vs baseline: 1.4182x; 1.4182x over previous
//
#include <hip/hip_runtime.h>
#include <hip/hip_bf16.h>
#include <math.h>

#define BATCH_N 8
#define SEQ_T   2048
#define DIM_D   1024
#define HS_N    128

using bf16x8_t = __attribute__((ext_vector_type(8))) __bf16;
using bf16x4_t = __attribute__((ext_vector_type(4))) __bf16;
using f32x4_t  = __attribute__((ext_vector_type(4))) float;

__device__ __forceinline__ f32x4_t mfma_16x16x32(bf16x8_t a, bf16x8_t b, f32x4_t c) {
  return __builtin_amdgcn_mfma_f32_16x16x32_bf16(a, b, c, 0, 0, 0);
}

// ---------------------------------------------------------------------------
// Kernel 0: cast W -> bf16, rows [K:0-127][Q:128-255][V:256-383], Q pre-scaled
// ---------------------------------------------------------------------------
__global__ __launch_bounds__(256) void castw_kernel(
    const float* __restrict__ Wk, const float* __restrict__ Wq,
    const float* __restrict__ Wv, __bf16* __restrict__ Wb) {
  int idx = blockIdx.x * 256 + threadIdx.x;
  int e   = idx * 4;
  int row = e >> 10;
  int col = e & 1023;
  const float* src;
  float sc = 1.0f;
  if (row < 128) {
    src = Wk + row * DIM_D + col;
  } else if (row < 256) {
    src = Wq + (row - 128) * DIM_D + col;
    sc  = 0.08838834764831845f;  // 1/sqrt(HS) folded into Wq
  } else {
    src = Wv + (row - 256) * DIM_D + col;
  }
  float4 v = *(const float4*)src;
  bf16x4_t o;
  o[0] = (__bf16)(v.x * sc); o[1] = (__bf16)(v.y * sc);
  o[2] = (__bf16)(v.z * sc); o[3] = (__bf16)(v.w * sc);
  *(bf16x4_t*)(Wb + e) = o;
}

// ---------------------------------------------------------------------------
// Kernel 1: projections. Block = 32 m-rows x 384 n-cols, 4 waves.
// Grid = 512 blocks (2 blocks/CU -> 2 waves/SIMD; v1 had 1 wave/SIMD).
// Wave w: n in [w*96, w*96+96) = 6 n-tiles; 2 m-tiles of 16.
// ---------------------------------------------------------------------------
__global__ __launch_bounds__(256) void proj_kernel(
    const float* __restrict__ x, const __bf16* __restrict__ Wb,
    __bf16* __restrict__ Qb, __bf16* __restrict__ Kb, __bf16* __restrict__ Vt) {
  const int lane = threadIdx.x & 63;
  const int wave = threadIdx.x >> 6;
  const int lr = lane & 15;
  const int lq = lane >> 4;
  const int m0 = blockIdx.x * 32;

  f32x4_t acc[2][6];
  #pragma unroll
  for (int mt = 0; mt < 2; ++mt)
    #pragma unroll
    for (int nt = 0; nt < 6; ++nt) acc[mt][nt] = (f32x4_t){0.f, 0.f, 0.f, 0.f};

  const float*  xb = x  + (size_t)(m0 + lr) * DIM_D + lq * 8;
  const __bf16* wb = Wb + (size_t)(wave * 96 + lr) * DIM_D + lq * 8;

  for (int ks = 0; ks < 32; ++ks) {
    const int k0 = ks * 32;
    bf16x8_t af[2];
    #pragma unroll
    for (int mt = 0; mt < 2; ++mt) {
      const float* p = xb + mt * 16 * DIM_D + k0;
      float4 f0 = *(const float4*)p;
      float4 f1 = *(const float4*)(p + 4);
      bf16x8_t a;
      a[0] = (__bf16)f0.x; a[1] = (__bf16)f0.y;
      a[2] = (__bf16)f0.z; a[3] = (__bf16)f0.w;
      a[4] = (__bf16)f1.x; a[5] = (__bf16)f1.y;
      a[6] = (__bf16)f1.z; a[7] = (__bf16)f1.w;
      af[mt] = a;
    }
    bf16x8_t bfr[6];
    #pragma unroll
    for (int nt = 0; nt < 6; ++nt)
      bfr[nt] = *(const bf16x8_t*)(wb + nt * 16 * DIM_D + k0);
    #pragma unroll
    for (int mt = 0; mt < 2; ++mt)
      #pragma unroll
      for (int nt = 0; nt < 6; ++nt)
        acc[mt][nt] = mfma_16x16x32(af[mt], bfr[nt], acc[mt][nt]);
  }

  #pragma unroll
  for (int mt = 0; mt < 2; ++mt) {
    const int rowb = m0 + mt * 16 + lq * 4;
    #pragma unroll
    for (int nt = 0; nt < 6; ++nt) {
      const int nn = wave * 96 + nt * 16 + lr;
      if (nn < 256) {
        __bf16* dst = (nn < 128) ? (Kb + nn) : (Qb + (nn - 128));
        #pragma unroll
        for (int r = 0; r < 4; ++r)
          dst[(size_t)(rowb + r) * HS_N] = (__bf16)acc[mt][nt][r];
      } else {
        const int bb = rowb >> 11;
        const int t0 = rowb & 2047;
        bf16x4_t o;
        #pragma unroll
        for (int r = 0; r < 4; ++r) o[r] = (__bf16)acc[mt][nt][r];
        *(bf16x4_t*)(Vt + (size_t)bb * (HS_N * SEQ_T) + (size_t)(nn - 256) * SEQ_T + t0) = o;
      }
    }
  }
}

// ---------------------------------------------------------------------------
// Kernel 2: flash attention, split-K across 4 waves.
// Block = 4 waves; handles q-tile pair (j, 127-j) -> constant work per block
// (129 key-units of 16). Each tile's key range is split 4 ways across waves
// (flash-decoding); partial (m,l,O) merged via LDS. 2048 waves = 8 waves/CU.
// ---------------------------------------------------------------------------
__global__ __launch_bounds__(256) void attn_kernel(
    const __bf16* __restrict__ Qb, const __bf16* __restrict__ Kb,
    const __bf16* __restrict__ Vt, float* __restrict__ out) {
  __shared__ float  Ocomb[4][16][132];   // [wave][row][col], padded stride
  __shared__ float  mcomb[4][16];
  __shared__ float  lcomb[4][16];
  __shared__ __bf16 pbuf[4][16 * 72];    // per-wave P C/D->A round-trip

  const int tid  = threadIdx.x;
  const int lane = tid & 63;
  const int wave = tid >> 6;
  const int lr = lane & 15;
  const int lq = lane >> 4;
  const int b  = blockIdx.x >> 6;
  const int p  = blockIdx.x & 63;

  const __bf16* Qbb = Qb + (size_t)b * (SEQ_T * HS_N);
  const __bf16* Kbb = Kb + (size_t)b * (SEQ_T * HS_N);
  const __bf16* Vbb = Vt + (size_t)b * (HS_N * SEQ_T);
  float* ob = out + (size_t)b * (SEQ_T * HS_N);
  __bf16* pb = pbuf[wave];

  for (int half = 0; half < 2; ++half) {
    const int j  = half ? (127 - p) : p;
    const int q0 = j * 16;
    const int nu = j + 1;                      // causal key-units of 16
    const int u_lo = (wave * nu) >> 2;         // this wave's unit range
    const int u_hi = ((wave + 1) * nu) >> 2;

    bf16x8_t qf[4];
    #pragma unroll
    for (int ks = 0; ks < 4; ++ks)
      qf[ks] = *(const bf16x8_t*)(Qbb + (size_t)(q0 + lr) * HS_N + ks * 32 + lq * 8);

    f32x4_t Oa[8];
    #pragma unroll
    for (int o = 0; o < 8; ++o) Oa[o] = (f32x4_t){0.f, 0.f, 0.f, 0.f};
    float mrow[4] = {-INFINITY, -INFINITY, -INFINITY, -INFINITY};
    float lrow[4] = {0.f, 0.f, 0.f, 0.f};

    for (int u = u_lo; u < u_hi; u += 4) {
      const int kk = u * 16;
      int nact = u_hi - u;
      if (nact > 4) nact = 4;

      // ---- QK^T (scale folded into Q) ----
      f32x4_t s[4];
      #pragma unroll
      for (int nt = 0; nt < 4; ++nt) {
        f32x4_t sv = (f32x4_t){0.f, 0.f, 0.f, 0.f};
        if (nt < nact) {
          const __bf16* kp = Kbb + (size_t)(kk + nt * 16 + lr) * HS_N + lq * 8;
          #pragma unroll
          for (int ks = 0; ks < 4; ++ks)
            sv = mfma_16x16x32(qf[ks], *(const bf16x8_t*)(kp + ks * 32), sv);
          const int col = kk + nt * 16 + lr;
          #pragma unroll
          for (int r = 0; r < 4; ++r)
            if (col > q0 + lq * 4 + r) sv[r] = -INFINITY;
        }
        s[nt] = sv;
      }

      // ---- issue V loads early (independent of softmax; hides latency) ----
      const int ksteps = (nact + 1) >> 1;
      bf16x8_t vf[2][8];
      #pragma unroll
      for (int k2 = 0; k2 < 2; ++k2) {
        if (k2 < ksteps) {
          int vk = kk + k2 * 32 + lq * 8;
          if (vk > SEQ_T - 8) vk = SEQ_T - 8;   // clamp; P=0 rows make it inert
          #pragma unroll
          for (int o = 0; o < 8; ++o)
            vf[k2][o] = *(const bf16x8_t*)(Vbb + (size_t)(o * 16 + lr) * SEQ_T + vk);
        }
      }

      // ---- online softmax (rows across 16-lane groups) ----
      float alpha[4];
      #pragma unroll
      for (int r = 0; r < 4; ++r) {
        float mv = mrow[r];
        #pragma unroll
        for (int nt = 0; nt < 4; ++nt)
          if (nt < nact) mv = fmaxf(mv, s[nt][r]);
        mv = fmaxf(mv, __shfl_xor(mv, 1));
        mv = fmaxf(mv, __shfl_xor(mv, 2));
        mv = fmaxf(mv, __shfl_xor(mv, 4));
        mv = fmaxf(mv, __shfl_xor(mv, 8));
        alpha[r] = __expf(mrow[r] - mv);
        mrow[r]  = mv;
      }
      float rs[4] = {0.f, 0.f, 0.f, 0.f};
      #pragma unroll
      for (int nt = 0; nt < 4; ++nt) {
        if (nt < nact) {
          #pragma unroll
          for (int r = 0; r < 4; ++r) {
            float pv = __expf(s[nt][r] - mrow[r]);
            s[nt][r] = pv;
            rs[r] += pv;
          }
        }
      }
      #pragma unroll
      for (int r = 0; r < 4; ++r) {
        rs[r] += __shfl_xor(rs[r], 1);
        rs[r] += __shfl_xor(rs[r], 2);
        rs[r] += __shfl_xor(rs[r], 4);
        rs[r] += __shfl_xor(rs[r], 8);
        lrow[r] = lrow[r] * alpha[r] + rs[r];
      }
      f32x4_t av = {alpha[0], alpha[1], alpha[2], alpha[3]};
      #pragma unroll
      for (int o = 0; o < 8; ++o) Oa[o] *= av;

      // ---- P: C/D layout -> LDS -> A layout ----
      #pragma unroll
      for (int nt = 0; nt < 4; ++nt) {
        #pragma unroll
        for (int r = 0; r < 4; ++r) {
          float pv = (nt < nact) ? s[nt][r] : 0.f;
          pb[(lq * 4 + r) * 72 + nt * 16 + lr] = (__bf16)pv;
        }
      }
      #pragma unroll
      for (int k2 = 0; k2 < 2; ++k2) {
        if (k2 < ksteps) {
          bf16x8_t afr = *(const bf16x8_t*)(pb + lr * 72 + k2 * 32 + lq * 8);
          #pragma unroll
          for (int o = 0; o < 8; ++o)
            Oa[o] = mfma_16x16x32(afr, vf[k2][o], Oa[o]);
        }
      }
    }

    // ---- write partials to LDS ----
    #pragma unroll
    for (int o = 0; o < 8; ++o)
      #pragma unroll
      for (int r = 0; r < 4; ++r)
        Ocomb[wave][lq * 4 + r][o * 16 + lr] = Oa[o][r];
    if (lr == 0) {
      #pragma unroll
      for (int r = 0; r < 4; ++r) {
        mcomb[wave][lq * 4 + r] = mrow[r];
        lcomb[wave][lq * 4 + r] = lrow[r];
      }
    }
    __syncthreads();

    // ---- merge 4 partials, normalize, store ----
    {
      const int row = tid >> 4;            // 0..15
      const int cb  = (tid & 15) * 8;      // 0..120
      float mw[4], sw[4];
      float mstar = -INFINITY;
      #pragma unroll
      for (int w = 0; w < 4; ++w) { mw[w] = mcomb[w][row]; mstar = fmaxf(mstar, mw[w]); }
      float ls = 0.f;
      #pragma unroll
      for (int w = 0; w < 4; ++w) { sw[w] = __expf(mw[w] - mstar); ls += sw[w] * lcomb[w][row]; }
      const float inv = 1.0f / ls;
      float accv[8];
      #pragma unroll
      for (int c = 0; c < 8; ++c) accv[c] = 0.f;
      #pragma unroll
      for (int w = 0; w < 4; ++w)
        #pragma unroll
        for (int c = 0; c < 8; ++c) accv[c] += sw[w] * Ocomb[w][row][cb + c];
      float* op = ob + (size_t)(q0 + row) * HS_N + cb;
      float4 o0 = {accv[0] * inv, accv[1] * inv, accv[2] * inv, accv[3] * inv};
      float4 o1 = {accv[4] * inv, accv[5] * inv, accv[6] * inv, accv[7] * inv};
      *(float4*)op       = o0;
      *(float4*)(op + 4) = o1;
    }
    __syncthreads();
  }
}

// ---------------------------------------------------------------------------
extern "C" void kernel_launch(void* const* d_in, const int* in_sizes, int n_in,
                              void* d_out, int out_size, void* d_ws, size_t ws_size,
                              hipStream_t stream) {
  const float* x  = (const float*)d_in[0];
  const float* Wk = (const float*)d_in[1];
  const float* Wq = (const float*)d_in[2];
  const float* Wv = (const float*)d_in[3];
  float* out = (float*)d_out;

  char* ws = (char*)d_ws;
  __bf16* Wb = (__bf16*)ws;                          //   786432 B
  __bf16* Qb = (__bf16*)(ws + 786432);               //  4194304 B
  __bf16* Kb = (__bf16*)(ws + 786432 + 4194304);     //  4194304 B
  __bf16* Vt = (__bf16*)(ws + 786432 + 8388608);     //  4194304 B

  castw_kernel<<<384, 256, 0, stream>>>(Wk, Wq, Wv, Wb);
  proj_kernel<<<BATCH_N * SEQ_T / 32, 256, 0, stream>>>(x, Wb, Qb, Kb, Vt);
  attn_kernel<<<BATCH_N * 64, 256, 0, stream>>>(Qb, Kb, Vt, out);
}

// Round 3
// 213.701 us; speedup vs baseline: 1.5530x; 1.0951x over previous
//
#include <hip/hip_runtime.h>
#include <hip/hip_bf16.h>
#include <math.h>

#define BATCH_N 8
#define SEQ_T   2048
#define DIM_D   1024
#define HS_N    128

using bf16x8_t = __attribute__((ext_vector_type(8))) __bf16;
using bf16x4_t = __attribute__((ext_vector_type(4))) __bf16;
using f32x4_t  = __attribute__((ext_vector_type(4))) float;

__device__ __forceinline__ f32x4_t mfma_16x16x32(bf16x8_t a, bf16x8_t b, f32x4_t c) {
  return __builtin_amdgcn_mfma_f32_16x16x32_bf16(a, b, c, 0, 0, 0);
}

// async global->LDS, 16B per lane; LDS dest is wave-uniform base + lane*16
__device__ __forceinline__ void async_cp16(const void* g, void* l) {
  __builtin_amdgcn_global_load_lds(
      (const __attribute__((address_space(1))) unsigned int*)g,
      (__attribute__((address_space(3))) unsigned int*)l, 16, 0, 0);
}

// ---------------------------------------------------------------------------
// Kernel 0: cast W -> bf16, rows [K:0-127][Q:128-255][V:256-383], Q pre-scaled
// ---------------------------------------------------------------------------
__global__ __launch_bounds__(256) void castw_kernel(
    const float* __restrict__ Wk, const float* __restrict__ Wq,
    const float* __restrict__ Wv, __bf16* __restrict__ Wb) {
  int idx = blockIdx.x * 256 + threadIdx.x;
  int e   = idx * 4;
  int row = e >> 10;
  int col = e & 1023;
  const float* src;
  float sc = 1.0f;
  if (row < 128) {
    src = Wk + row * DIM_D + col;
  } else if (row < 256) {
    src = Wq + (row - 128) * DIM_D + col;
    sc  = 0.08838834764831845f;  // 1/sqrt(HS) folded into Wq
  } else {
    src = Wv + (row - 256) * DIM_D + col;
  }
  float4 v = *(const float4*)src;
  bf16x4_t o;
  o[0] = (__bf16)(v.x * sc); o[1] = (__bf16)(v.y * sc);
  o[2] = (__bf16)(v.z * sc); o[3] = (__bf16)(v.w * sc);
  *(bf16x4_t*)(Wb + e) = o;
}

// ---------------------------------------------------------------------------
// Kernel 1: projections, m97-style LDS-staged GEMM.
// Tile 128m x 96n, BK=64, grid = 128 mb x 4 nb = 512 blocks (2/CU balanced).
// A = x fp32 staged via global_load_lds (swizzled), converted on frag read.
// B = Wb bf16 staged via global_load_lds (swizzled).
// Wave (2x2): wm=w&1 (64 m-rows), wn=w>>1 (48 n-cols); 4x3 MFMA tiles.
// ---------------------------------------------------------------------------
__global__ __launch_bounds__(256, 2) void proj_kernel(
    const float* __restrict__ x, const __bf16* __restrict__ Wb,
    __bf16* __restrict__ Qb, __bf16* __restrict__ Kb, __bf16* __restrict__ Vt) {
  __shared__ float  As[128 * 64];   // 32 KB, 256B rows, 16B-unit swizzle: phys = log ^ (row&15)
  __shared__ __bf16 Bs[96 * 64];    // 12 KB, 128B rows, 16B-unit swizzle: phys = log ^ (row&7)

  const int lane = threadIdx.x & 63;
  const int wave = threadIdx.x >> 6;
  const int lr = lane & 15;
  const int lq = lane >> 4;
  const int wm = wave & 1;
  const int wn = wave >> 1;
  const int m0 = (blockIdx.x >> 2) * 128;
  const int n0 = (blockIdx.x & 3) * 96;

  f32x4_t acc[4][3];
  #pragma unroll
  for (int mt = 0; mt < 4; ++mt)
    #pragma unroll
    for (int nt = 0; nt < 3; ++nt) acc[mt][nt] = (f32x4_t){0.f, 0.f, 0.f, 0.f};

  for (int kt = 0; kt < 16; ++kt) {
    const int kk = kt * 64;
    __syncthreads();
    // staging: A = 32 calls of 1KB (4 rows x 256B), B = 12 calls (8 rows x 128B)
    for (int c = wave; c < 44; c += 4) {
      if (c < 32) {
        const int row = c * 4 + (lane >> 4);
        const int lb  = (lane & 15) ^ (row & 15);
        async_cp16(x + (size_t)(m0 + row) * DIM_D + kk + lb * 4, As + c * 256);
      } else {
        const int c2  = c - 32;
        const int row = c2 * 8 + (lane >> 3);
        const int lb  = (lane & 7) ^ (row & 7);
        async_cp16(Wb + (size_t)(n0 + row) * DIM_D + kk + lb * 8, Bs + c2 * 512);
      }
    }
    __syncthreads();

    #pragma unroll
    for (int c32 = 0; c32 < 2; ++c32) {
      bf16x8_t af[4];
      #pragma unroll
      for (int mt = 0; mt < 4; ++mt) {
        const int ml = wm * 64 + mt * 16 + lr;
        const int sw = ml & 15;
        const int l0 = c32 * 8 + lq * 2;
        float4 f0 = *(const float4*)(As + ml * 64 + ((l0    ) ^ sw) * 4);
        float4 f1 = *(const float4*)(As + ml * 64 + ((l0 + 1) ^ sw) * 4);
        bf16x8_t a;
        a[0] = (__bf16)f0.x; a[1] = (__bf16)f0.y;
        a[2] = (__bf16)f0.z; a[3] = (__bf16)f0.w;
        a[4] = (__bf16)f1.x; a[5] = (__bf16)f1.y;
        a[6] = (__bf16)f1.z; a[7] = (__bf16)f1.w;
        af[mt] = a;
      }
      bf16x8_t bfv[3];
      #pragma unroll
      for (int nt = 0; nt < 3; ++nt) {
        const int nl = wn * 48 + nt * 16 + lr;
        bfv[nt] = *(const bf16x8_t*)(Bs + nl * 64 + (((c32 * 4 + lq) ^ (nl & 7)) * 8));
      }
      #pragma unroll
      for (int mt = 0; mt < 4; ++mt)
        #pragma unroll
        for (int nt = 0; nt < 3; ++nt)
          acc[mt][nt] = mfma_16x16x32(af[mt], bfv[nt], acc[mt][nt]);
    }
  }

  // epilogue: D tile (mt,nt): t = m0+wm*64+mt*16+lq*4+r, n = n0+wn*48+nt*16+lr
  #pragma unroll
  for (int mt = 0; mt < 4; ++mt) {
    const int t0 = m0 + wm * 64 + mt * 16 + lq * 4;
    #pragma unroll
    for (int nt = 0; nt < 3; ++nt) {
      const int nn = n0 + wn * 48 + nt * 16 + lr;
      if (nn < 256) {
        __bf16* dst = (nn < 128) ? (Kb + nn) : (Qb + (nn - 128));
        #pragma unroll
        for (int r = 0; r < 4; ++r)
          dst[(size_t)(t0 + r) * HS_N] = (__bf16)acc[mt][nt][r];
      } else {
        const int bb = t0 >> 11;
        const int tl = t0 & 2047;
        bf16x4_t o;
        #pragma unroll
        for (int r = 0; r < 4; ++r) o[r] = (__bf16)acc[mt][nt][r];
        *(bf16x4_t*)(Vt + (size_t)bb * (HS_N * SEQ_T) + (size_t)(nn - 256) * SEQ_T + tl) = o;
      }
    }
  }
}

// ---------------------------------------------------------------------------
// Kernel 2: flash attention v3.
// Grid 1024 = 8 batches x 128 q-tiles, heavy-j-first (j = 127 - blk/8).
// Block = 4 waves, keys of the tile split 4 ways; branchless full-chunk loop
// (no masking needed strictly below the diagonal) + one masked tail chunk.
// l-reduction deferred to after the loop. LDS 34.3 KB -> 4 blocks/CU.
// ---------------------------------------------------------------------------
__global__ __launch_bounds__(256, 4) void attn_kernel(
    const __bf16* __restrict__ Qb, const __bf16* __restrict__ Kb,
    const __bf16* __restrict__ Vt, float* __restrict__ out) {
  __shared__ float smem[4 * 16 * 132 + 128];  // Ocomb[4][16][132] + m/l[4][16]
  const int tid  = threadIdx.x;
  const int lane = tid & 63;
  const int wave = tid >> 6;
  const int lr = lane & 15;
  const int lq = lane >> 4;
  const int j  = 127 - (blockIdx.x >> 3);   // heavy blocks dispatched first
  const int b  = blockIdx.x & 7;
  const int q0 = j * 16;

  const __bf16* Qbb = Qb + (size_t)b * (SEQ_T * HS_N);
  const __bf16* Kbb = Kb + (size_t)b * (SEQ_T * HS_N);
  const __bf16* Vbb = Vt + (size_t)b * (HS_N * SEQ_T);
  float* ob = out + (size_t)b * (SEQ_T * HS_N);

  float* mcomb = smem + 8448;
  float* lcomb = smem + 8448 + 64;
  // pbuf aliased into this wave's own Ocomb slice (written only after all
  // pbuf reads by this wave; no cross-wave overlap; merge is post-barrier)
  __bf16* pb = (__bf16*)(smem + wave * 2112);

  bf16x8_t qf[4];
  #pragma unroll
  for (int ks = 0; ks < 4; ++ks)
    qf[ks] = *(const bf16x8_t*)(Qbb + (size_t)(q0 + lr) * HS_N + ks * 32 + lq * 8);

  f32x4_t Oa[8];
  #pragma unroll
  for (int o = 0; o < 8; ++o) Oa[o] = (f32x4_t){0.f, 0.f, 0.f, 0.f};
  float mrow[4] = {-INFINITY, -INFINITY, -INFINITY, -INFINITY};
  float lsum[4] = {0.f, 0.f, 0.f, 0.f};   // per-lane partial; reduced after loop

  const int nu = j + 1;
  const int u_lo = (wave * nu) >> 2;
  const int u_hi = ((wave + 1) * nu) >> 2;
  const int n_units = u_hi - u_lo;
  int n_full = 0, n_tail = 0;
  if (n_units > 0) { n_full = (n_units - 1) >> 2; n_tail = n_units - 4 * n_full; }
  int kk = u_lo * 16;

  // ---- full chunks: 64 keys, strictly below diagonal, branchless ----
  for (int it = 0; it < n_full; ++it, kk += 64) {
    f32x4_t s[4];
    #pragma unroll
    for (int nt = 0; nt < 4; ++nt) s[nt] = (f32x4_t){0.f, 0.f, 0.f, 0.f};
    #pragma unroll
    for (int ks = 0; ks < 4; ++ks)
      #pragma unroll
      for (int nt = 0; nt < 4; ++nt) {
        bf16x8_t kf = *(const bf16x8_t*)(Kbb + (size_t)(kk + nt * 16 + lr) * HS_N + ks * 32 + lq * 8);
        s[nt] = mfma_16x16x32(qf[ks], kf, s[nt]);
      }

    float alpha[4];
    #pragma unroll
    for (int r = 0; r < 4; ++r) {
      float mv = fmaxf(fmaxf(s[0][r], s[1][r]), fmaxf(s[2][r], s[3][r]));
      mv = fmaxf(mv, __shfl_xor(mv, 1));
      mv = fmaxf(mv, __shfl_xor(mv, 2));
      mv = fmaxf(mv, __shfl_xor(mv, 4));
      mv = fmaxf(mv, __shfl_xor(mv, 8));
      mv = fmaxf(mv, mrow[r]);
      alpha[r] = __expf(mrow[r] - mv);
      mrow[r]  = mv;
    }
    #pragma unroll
    for (int r = 0; r < 4; ++r) {
      float p0 = __expf(s[0][r] - mrow[r]);
      float p1 = __expf(s[1][r] - mrow[r]);
      float p2 = __expf(s[2][r] - mrow[r]);
      float p3 = __expf(s[3][r] - mrow[r]);
      s[0][r] = p0; s[1][r] = p1; s[2][r] = p2; s[3][r] = p3;
      lsum[r] = lsum[r] * alpha[r] + ((p0 + p1) + (p2 + p3));
    }
    f32x4_t av = {alpha[0], alpha[1], alpha[2], alpha[3]};
    #pragma unroll
    for (int o = 0; o < 8; ++o) Oa[o] *= av;

    #pragma unroll
    for (int nt = 0; nt < 4; ++nt)
      #pragma unroll
      for (int r = 0; r < 4; ++r)
        pb[(lq * 4 + r) * 72 + nt * 16 + lr] = (__bf16)s[nt][r];

    #pragma unroll
    for (int k2 = 0; k2 < 2; ++k2) {
      bf16x8_t afr = *(const bf16x8_t*)(pb + lr * 72 + k2 * 32 + lq * 8);
      #pragma unroll
      for (int o = 0; o < 8; ++o) {
        bf16x8_t vfr = *(const bf16x8_t*)(Vbb + (size_t)(o * 16 + lr) * SEQ_T + kk + k2 * 32 + lq * 8);
        Oa[o] = mfma_16x16x32(afr, vfr, Oa[o]);
      }
    }
  }

  // ---- tail chunk: 1..4 units, includes diagonal masking ----
  if (n_tail > 0) {
    f32x4_t s[4];
    #pragma unroll
    for (int nt = 0; nt < 4; ++nt) {
      f32x4_t sv = (f32x4_t){0.f, 0.f, 0.f, 0.f};
      if (nt < n_tail) {
        #pragma unroll
        for (int ks = 0; ks < 4; ++ks) {
          bf16x8_t kf = *(const bf16x8_t*)(Kbb + (size_t)(kk + nt * 16 + lr) * HS_N + ks * 32 + lq * 8);
          sv = mfma_16x16x32(qf[ks], kf, sv);
        }
        const int col = kk + nt * 16 + lr;
        #pragma unroll
        for (int r = 0; r < 4; ++r)
          if (col > q0 + lq * 4 + r) sv[r] = -INFINITY;
      }
      s[nt] = sv;
    }
    float alpha[4];
    #pragma unroll
    for (int r = 0; r < 4; ++r) {
      float mv = mrow[r];
      #pragma unroll
      for (int nt = 0; nt < 4; ++nt)
        if (nt < n_tail) mv = fmaxf(mv, s[nt][r]);
      mv = fmaxf(mv, __shfl_xor(mv, 1));
      mv = fmaxf(mv, __shfl_xor(mv, 2));
      mv = fmaxf(mv, __shfl_xor(mv, 4));
      mv = fmaxf(mv, __shfl_xor(mv, 8));
      alpha[r] = __expf(mrow[r] - mv);
      mrow[r]  = mv;
    }
    float rs[4] = {0.f, 0.f, 0.f, 0.f};
    #pragma unroll
    for (int nt = 0; nt < 4; ++nt)
      if (nt < n_tail) {
        #pragma unroll
        for (int r = 0; r < 4; ++r) {
          float pv = __expf(s[nt][r] - mrow[r]);
          s[nt][r] = pv;
          rs[r] += pv;
        }
      }
    #pragma unroll
    for (int r = 0; r < 4; ++r) lsum[r] = lsum[r] * alpha[r] + rs[r];
    f32x4_t av = {alpha[0], alpha[1], alpha[2], alpha[3]};
    #pragma unroll
    for (int o = 0; o < 8; ++o) Oa[o] *= av;

    #pragma unroll
    for (int nt = 0; nt < 4; ++nt)
      #pragma unroll
      for (int r = 0; r < 4; ++r)
        pb[(lq * 4 + r) * 72 + nt * 16 + lr] = (__bf16)((nt < n_tail) ? s[nt][r] : 0.f);

    const int ksteps = (n_tail + 1) >> 1;
    #pragma unroll
    for (int k2 = 0; k2 < 2; ++k2)
      if (k2 < ksteps) {
        bf16x8_t afr = *(const bf16x8_t*)(pb + lr * 72 + k2 * 32 + lq * 8);
        int vk = kk + k2 * 32 + lq * 8;
        if (vk > SEQ_T - 8) vk = SEQ_T - 8;  // only clamps lanes whose P cols are 0
        #pragma unroll
        for (int o = 0; o < 8; ++o) {
          bf16x8_t vfr = *(const bf16x8_t*)(Vbb + (size_t)(o * 16 + lr) * SEQ_T + vk);
          Oa[o] = mfma_16x16x32(afr, vfr, Oa[o]);
        }
      }
  }

  // ---- deferred l reduction across the 16-lane row group ----
  float lrow[4];
  #pragma unroll
  for (int r = 0; r < 4; ++r) {
    float v = lsum[r];
    v += __shfl_xor(v, 1);
    v += __shfl_xor(v, 2);
    v += __shfl_xor(v, 4);
    v += __shfl_xor(v, 8);
    lrow[r] = v;
  }

  // ---- write partials (into own Ocomb slice; pbuf no longer needed) ----
  #pragma unroll
  for (int o = 0; o < 8; ++o)
    #pragma unroll
    for (int r = 0; r < 4; ++r)
      smem[wave * 2112 + (lq * 4 + r) * 132 + o * 16 + lr] = Oa[o][r];
  if (lr == 0) {
    #pragma unroll
    for (int r = 0; r < 4; ++r) {
      mcomb[wave * 16 + lq * 4 + r] = mrow[r];
      lcomb[wave * 16 + lq * 4 + r] = lrow[r];
    }
  }
  __syncthreads();

  // ---- merge 4 partials, normalize, store ----
  {
    const int row = tid >> 4;
    const int cb  = (tid & 15) * 8;
    float mw[4], sw[4];
    float mstar = -INFINITY;
    #pragma unroll
    for (int w = 0; w < 4; ++w) { mw[w] = mcomb[w * 16 + row]; mstar = fmaxf(mstar, mw[w]); }
    float ls = 0.f;
    #pragma unroll
    for (int w = 0; w < 4; ++w) { sw[w] = __expf(mw[w] - mstar); ls += sw[w] * lcomb[w * 16 + row]; }
    const float inv = 1.0f / ls;
    float accv[8];
    #pragma unroll
    for (int c = 0; c < 8; ++c) accv[c] = 0.f;
    #pragma unroll
    for (int w = 0; w < 4; ++w)
      #pragma unroll
      for (int c = 0; c < 8; ++c) accv[c] += sw[w] * smem[w * 2112 + row * 132 + cb + c];
    float* op = ob + (size_t)(q0 + row) * HS_N + cb;
    float4 o0 = {accv[0] * inv, accv[1] * inv, accv[2] * inv, accv[3] * inv};
    float4 o1 = {accv[4] * inv, accv[5] * inv, accv[6] * inv, accv[7] * inv};
    *(float4*)op       = o0;
    *(float4*)(op + 4) = o1;
  }
}

// ---------------------------------------------------------------------------
extern "C" void kernel_launch(void* const* d_in, const int* in_sizes, int n_in,
                              void* d_out, int out_size, void* d_ws, size_t ws_size,
                              hipStream_t stream) {
  const float* x  = (const float*)d_in[0];
  const float* Wk = (const float*)d_in[1];
  const float* Wq = (const float*)d_in[2];
  const float* Wv = (const float*)d_in[3];
  float* out = (float*)d_out;

  char* ws = (char*)d_ws;
  __bf16* Wb = (__bf16*)ws;                          //   786432 B
  __bf16* Qb = (__bf16*)(ws + 786432);               //  4194304 B
  __bf16* Kb = (__bf16*)(ws + 786432 + 4194304);     //  4194304 B
  __bf16* Vt = (__bf16*)(ws + 786432 + 8388608);     //  4194304 B

  castw_kernel<<<384, 256, 0, stream>>>(Wk, Wq, Wv, Wb);
  proj_kernel<<<512, 256, 0, stream>>>(x, Wb, Qb, Kb, Vt);
  attn_kernel<<<BATCH_N * 128, 256, 0, stream>>>(Qb, Kb, Vt, out);
}

// Round 5
// 197.272 us; speedup vs baseline: 1.6824x; 1.0833x over previous
//
#include <hip/hip_runtime.h>
#include <hip/hip_bf16.h>
#include <math.h>

#define BATCH_N 8
#define SEQ_T   2048
#define DIM_D   1024
#define HS_N    128

using bf16x8_t = __attribute__((ext_vector_type(8))) __bf16;
using bf16x4_t = __attribute__((ext_vector_type(4))) __bf16;
using f32x4_t  = __attribute__((ext_vector_type(4))) float;

__device__ __forceinline__ f32x4_t mfma_16x16x32(bf16x8_t a, bf16x8_t b, f32x4_t c) {
  return __builtin_amdgcn_mfma_f32_16x16x32_bf16(a, b, c, 0, 0, 0);
}

// async global->LDS, 16B/lane; LDS dest = wave-uniform base + lane*16
__device__ __forceinline__ void async_cp16(const void* g, void* l) {
  __builtin_amdgcn_global_load_lds(
      (const __attribute__((address_space(1))) unsigned int*)g,
      (__attribute__((address_space(3))) unsigned int*)l, 16, 0, 0);
}

// ---------------------------------------------------------------------------
// Kernel 0: cast W -> bf16, rows [K:0-127][Q:128-255][V:256-383], Q pre-scaled
// ---------------------------------------------------------------------------
__global__ __launch_bounds__(256) void castw_kernel(
    const float* __restrict__ Wk, const float* __restrict__ Wq,
    const float* __restrict__ Wv, __bf16* __restrict__ Wb) {
  int idx = blockIdx.x * 256 + threadIdx.x;
  int e   = idx * 4;
  int row = e >> 10;
  int col = e & 1023;
  const float* src;
  float sc = 1.0f;
  if (row < 128) {
    src = Wk + row * DIM_D + col;
  } else if (row < 256) {
    src = Wq + (row - 128) * DIM_D + col;
    sc  = 0.08838834764831845f;  // 1/sqrt(HS) folded into Wq
  } else {
    src = Wv + (row - 256) * DIM_D + col;
  }
  float4 v = *(const float4*)src;
  bf16x4_t o;
  o[0] = (__bf16)(v.x * sc); o[1] = (__bf16)(v.y * sc);
  o[2] = (__bf16)(v.z * sc); o[3] = (__bf16)(v.w * sc);
  *(bf16x4_t*)(Wb + e) = o;
}

// ---------------------------------------------------------------------------
// Kernel 1: projections. Tile 128m x 96n, BK=32, double-buffered LDS staging
// via global_load_lds (stage kt+1 after barrier, compute kt, barrier drains).
// Grid 512. A = x fp32 (cvt on frag read), B = Wb bf16. XOR-swizzled stages.
// ---------------------------------------------------------------------------
__global__ __launch_bounds__(256, 2) void proj_kernel(
    const float* __restrict__ x, const __bf16* __restrict__ Wb,
    __bf16* __restrict__ Qb, __bf16* __restrict__ Kb, __bf16* __restrict__ Vt) {
  __shared__ float  As[2][128 * 32];   // 16KB per buf, 128B rows, 16B-unit swz ^(row&7)
  __shared__ __bf16 Bs[2][96 * 32];    // 6KB per buf, 64B rows, 16B-unit swz ^(row&3)

  const int lane = threadIdx.x & 63;
  const int wave = threadIdx.x >> 6;
  const int lr = lane & 15;
  const int lq = lane >> 4;
  const int wm = wave & 1;
  const int wn = wave >> 1;
  const int m0 = (blockIdx.x >> 2) * 128;
  const int n0 = (blockIdx.x & 3) * 96;

  f32x4_t acc[4][3];
  #pragma unroll
  for (int mt = 0; mt < 4; ++mt)
    #pragma unroll
    for (int nt = 0; nt < 3; ++nt) acc[mt][nt] = (f32x4_t){0.f, 0.f, 0.f, 0.f};

  auto stage = [&](int bufi, int kt) {
    for (int c = wave; c < 22; c += 4) {
      if (c < 16) {            // A: 8 rows x 128B per call
        const int row = c * 8 + (lane >> 3);
        const int u   = (lane & 7) ^ (row & 7);
        async_cp16(x + (size_t)(m0 + row) * DIM_D + kt * 32 + u * 4,
                   &As[bufi][c * 256]);
      } else {                 // B: 16 rows x 64B per call
        const int c2  = c - 16;
        const int row = c2 * 16 + (lane >> 2);
        const int u   = (lane & 3) ^ (row & 3);
        async_cp16(Wb + (size_t)(n0 + row) * DIM_D + kt * 32 + u * 8,
                   &Bs[bufi][c2 * 512]);
      }
    }
  };

  stage(0, 0);
  __syncthreads();

  for (int kt = 0; kt < 32; ++kt) {
    const int cur = kt & 1;
    if (kt + 1 < 32) stage(cur ^ 1, kt + 1);

    bf16x8_t af[4];
    #pragma unroll
    for (int mt = 0; mt < 4; ++mt) {
      const int ml = wm * 64 + mt * 16 + lr;
      const int sw = ml & 7;
      float4 f0 = *(const float4*)(&As[cur][ml * 32 + (((2 * lq)     ^ sw) * 4)]);
      float4 f1 = *(const float4*)(&As[cur][ml * 32 + (((2 * lq + 1) ^ sw) * 4)]);
      bf16x8_t a;
      a[0] = (__bf16)f0.x; a[1] = (__bf16)f0.y;
      a[2] = (__bf16)f0.z; a[3] = (__bf16)f0.w;
      a[4] = (__bf16)f1.x; a[5] = (__bf16)f1.y;
      a[6] = (__bf16)f1.z; a[7] = (__bf16)f1.w;
      af[mt] = a;
    }
    bf16x8_t bfv[3];
    #pragma unroll
    for (int nt = 0; nt < 3; ++nt) {
      const int nl = wn * 48 + nt * 16 + lr;
      bfv[nt] = *(const bf16x8_t*)(&Bs[cur][nl * 32 + ((lq ^ (nl & 3)) * 8)]);
    }
    #pragma unroll
    for (int mt = 0; mt < 4; ++mt)
      #pragma unroll
      for (int nt = 0; nt < 3; ++nt)
        acc[mt][nt] = mfma_16x16x32(af[mt], bfv[nt], acc[mt][nt]);
    __syncthreads();
  }

  #pragma unroll
  for (int mt = 0; mt < 4; ++mt) {
    const int t0 = m0 + wm * 64 + mt * 16 + lq * 4;
    #pragma unroll
    for (int nt = 0; nt < 3; ++nt) {
      const int nn = n0 + wn * 48 + nt * 16 + lr;
      if (nn < 256) {
        __bf16* dst = (nn < 128) ? (Kb + nn) : (Qb + (nn - 128));
        #pragma unroll
        for (int r = 0; r < 4; ++r)
          dst[(size_t)(t0 + r) * HS_N] = (__bf16)acc[mt][nt][r];
      } else {
        const int bb = t0 >> 11;
        const int tl = t0 & 2047;
        bf16x4_t o;
        #pragma unroll
        for (int r = 0; r < 4; ++r) o[r] = (__bf16)acc[mt][nt][r];
        *(bf16x4_t*)(Vt + (size_t)bb * (HS_N * SEQ_T) + (size_t)(nn - 256) * SEQ_T + tl) = o;
      }
    }
  }
}

// ---------------------------------------------------------------------------
// Kernel 2: flash attention v4.1. Block = 2 waves = 32 q-rows (each wave owns
// a 16-row tile; NO cross-wave merge). K/V 64-key chunks staged to LDS (wave 0
// stages K, wave 1 stages V) double-buffered: stage(c+1) after barrier,
// compute(c) from LDS only, barrier drains. Grid 512 = 8 batch x 64 q-groups,
// heavy+light paired. FIX vs v4: causal-mask gate is kk+63 > q0 (chunk max
// col vs tile MIN row); v4's kk+48 > q0 left the diagonal chunk of every
// q0 == 48 (mod 64) tile unmasked -> absmax 0.149 leak.
// ---------------------------------------------------------------------------
__global__ __launch_bounds__(128) void attn_kernel(
    const __bf16* __restrict__ Qb, const __bf16* __restrict__ Kb,
    const __bf16* __restrict__ Vt, float* __restrict__ out) {
  __shared__ __bf16 Ks[2][64 * 128];   // 16KB per buf; 256B rows, swz ^(row&15)
  __shared__ __bf16 Vs[2][128 * 64];   // 16KB per buf; 128B rows, swz ^(row&7)
  __shared__ __bf16 pbuf[2][16 * 72];  // per-wave P C/D->A round-trip

  const int lane = threadIdx.x & 63;
  const int wave = threadIdx.x >> 6;       // 0..1
  const int lr = lane & 15;
  const int lq = lane >> 4;
  const int b  = blockIdx.x & 7;
  const int r  = blockIdx.x >> 3;                    // 0..63
  const int jg = (r < 32) ? (63 - r) : (r - 32);     // heavy first + pairing
  const int q0 = jg * 32 + wave * 16;
  const int C  = (jg * 32 + 95) >> 6;                // 64-key chunks

  const __bf16* Qbb = Qb + (size_t)b * (SEQ_T * HS_N);
  const __bf16* Kbb = Kb + (size_t)b * (SEQ_T * HS_N);
  const __bf16* Vbb = Vt + (size_t)b * (HS_N * SEQ_T);
  float* ob = out + (size_t)b * (SEQ_T * HS_N);
  __bf16* pb = pbuf[wave];

  bf16x8_t qf[4];
  #pragma unroll
  for (int ks = 0; ks < 4; ++ks)
    qf[ks] = *(const bf16x8_t*)(Qbb + (size_t)(q0 + lr) * HS_N + ks * 32 + lq * 8);

  f32x4_t Oa[8];
  #pragma unroll
  for (int o = 0; o < 8; ++o) Oa[o] = (f32x4_t){0.f, 0.f, 0.f, 0.f};
  float mrow[4] = {-INFINITY, -INFINITY, -INFINITY, -INFINITY};
  float lsum[4] = {0.f, 0.f, 0.f, 0.f};

  auto stage = [&](int bufi, int c) {
    const int kk = c * 64;
    if (wave == 0) {                 // K: 64 rows x 256B
      #pragma unroll
      for (int i = 0; i < 16; ++i) {
        const int row = i * 4 + (lane >> 4);
        const int u   = (lane & 15) ^ (row & 15);
        async_cp16(Kbb + (size_t)(kk + row) * HS_N + u * 8, &Ks[bufi][i * 512]);
      }
    } else {                         // V: 128 rows x 128B (rows are HS dims)
      #pragma unroll
      for (int i = 0; i < 16; ++i) {
        const int row = i * 8 + (lane >> 3);
        const int u   = (lane & 7) ^ (row & 7);
        async_cp16(Vbb + (size_t)row * SEQ_T + kk + u * 8, &Vs[bufi][i * 512]);
      }
    }
  };

  stage(0, 0);
  __syncthreads();

  for (int c = 0; c < C; ++c) {
    const int cur = c & 1;
    if (c + 1 < C) stage(cur ^ 1, c + 1);
    const int kk = c * 64;

    // ---- QK^T from LDS (scale folded into Q) ----
    f32x4_t s[4];
    #pragma unroll
    for (int nt = 0; nt < 4; ++nt) s[nt] = (f32x4_t){0.f, 0.f, 0.f, 0.f};
    #pragma unroll
    for (int ks = 0; ks < 4; ++ks)
      #pragma unroll
      for (int nt = 0; nt < 4; ++nt) {
        bf16x8_t kf = *(const bf16x8_t*)(
            &Ks[cur][(nt * 16 + lr) * 128 + (((ks * 4 + lq) ^ lr) * 8)]);
        s[nt] = mfma_16x16x32(qf[ks], kf, s[nt]);
      }
    if (kk + 63 > q0) {  // mask whenever chunk max col can exceed tile min row
      #pragma unroll
      for (int nt = 0; nt < 4; ++nt) {
        const int col = kk + nt * 16 + lr;
        #pragma unroll
        for (int r2 = 0; r2 < 4; ++r2)
          if (col > q0 + lq * 4 + r2) s[nt][r2] = -INFINITY;
      }
    }

    // ---- online softmax ----
    float alpha[4];
    #pragma unroll
    for (int r2 = 0; r2 < 4; ++r2) {
      float mv = fmaxf(fmaxf(s[0][r2], s[1][r2]), fmaxf(s[2][r2], s[3][r2]));
      mv = fmaxf(mv, __shfl_xor(mv, 1));
      mv = fmaxf(mv, __shfl_xor(mv, 2));
      mv = fmaxf(mv, __shfl_xor(mv, 4));
      mv = fmaxf(mv, __shfl_xor(mv, 8));
      mv = fmaxf(mv, mrow[r2]);
      alpha[r2] = __expf(mrow[r2] - mv);
      mrow[r2]  = mv;
    }
    #pragma unroll
    for (int r2 = 0; r2 < 4; ++r2) {
      float p0 = __expf(s[0][r2] - mrow[r2]);
      float p1 = __expf(s[1][r2] - mrow[r2]);
      float p2 = __expf(s[2][r2] - mrow[r2]);
      float p3 = __expf(s[3][r2] - mrow[r2]);
      s[0][r2] = p0; s[1][r2] = p1; s[2][r2] = p2; s[3][r2] = p3;
      lsum[r2] = lsum[r2] * alpha[r2] + ((p0 + p1) + (p2 + p3));
    }
    f32x4_t av = {alpha[0], alpha[1], alpha[2], alpha[3]};
    #pragma unroll
    for (int o = 0; o < 8; ++o) Oa[o] *= av;

    // ---- P: C/D -> LDS -> A layout; PV from LDS ----
    #pragma unroll
    for (int nt = 0; nt < 4; ++nt)
      #pragma unroll
      for (int r2 = 0; r2 < 4; ++r2)
        pb[(lq * 4 + r2) * 72 + nt * 16 + lr] = (__bf16)s[nt][r2];

    #pragma unroll
    for (int k2 = 0; k2 < 2; ++k2) {
      bf16x8_t afr = *(const bf16x8_t*)(pb + lr * 72 + k2 * 32 + lq * 8);
      #pragma unroll
      for (int o = 0; o < 8; ++o) {
        bf16x8_t vfr = *(const bf16x8_t*)(
            &Vs[cur][(o * 16 + lr) * 64 + (((k2 * 4 + lq) ^ (lr & 7)) * 8)]);
        Oa[o] = mfma_16x16x32(afr, vfr, Oa[o]);
      }
    }
    __syncthreads();   // drains stage(c+1); protects buffer reuse
  }

  // ---- l reduction + normalize + store (no cross-wave merge) ----
  #pragma unroll
  for (int r2 = 0; r2 < 4; ++r2) {
    float v = lsum[r2];
    v += __shfl_xor(v, 1);
    v += __shfl_xor(v, 2);
    v += __shfl_xor(v, 4);
    v += __shfl_xor(v, 8);
    const float inv = 1.0f / v;
    const int rowg = q0 + lq * 4 + r2;
    #pragma unroll
    for (int o = 0; o < 8; ++o)
      ob[(size_t)rowg * HS_N + o * 16 + lr] = Oa[o][r2] * inv;
  }
}

// ---------------------------------------------------------------------------
extern "C" void kernel_launch(void* const* d_in, const int* in_sizes, int n_in,
                              void* d_out, int out_size, void* d_ws, size_t ws_size,
                              hipStream_t stream) {
  const float* x  = (const float*)d_in[0];
  const float* Wk = (const float*)d_in[1];
  const float* Wq = (const float*)d_in[2];
  const float* Wv = (const float*)d_in[3];
  float* out = (float*)d_out;

  char* ws = (char*)d_ws;
  __bf16* Wb = (__bf16*)ws;                          //   786432 B
  __bf16* Qb = (__bf16*)(ws + 786432);               //  4194304 B
  __bf16* Kb = (__bf16*)(ws + 786432 + 4194304);     //  4194304 B
  __bf16* Vt = (__bf16*)(ws + 786432 + 8388608);     //  4194304 B

  castw_kernel<<<384, 256, 0, stream>>>(Wk, Wq, Wv, Wb);
  proj_kernel<<<512, 256, 0, stream>>>(x, Wb, Qb, Kb, Vt);
  attn_kernel<<<512, 128, 0, stream>>>(Qb, Kb, Vt, out);
}

// Round 6
// 184.669 us; speedup vs baseline: 1.7972x; 1.0682x over previous
//
#include <hip/hip_runtime.h>
#include <hip/hip_bf16.h>
#include <math.h>

#define BATCH_N 8
#define SEQ_T   2048
#define DIM_D   1024
#define HS_N    128

using bf16x8_t = __attribute__((ext_vector_type(8))) __bf16;
using bf16x4_t = __attribute__((ext_vector_type(4))) __bf16;
using f32x4_t  = __attribute__((ext_vector_type(4))) float;

__device__ __forceinline__ f32x4_t mfma_16x16x32(bf16x8_t a, bf16x8_t b, f32x4_t c) {
  return __builtin_amdgcn_mfma_f32_16x16x32_bf16(a, b, c, 0, 0, 0);
}

// async global->LDS, 16B/lane; LDS dest = wave-uniform base + lane*16
__device__ __forceinline__ void async_cp16(const void* g, void* l) {
  __builtin_amdgcn_global_load_lds(
      (const __attribute__((address_space(1))) unsigned int*)g,
      (__attribute__((address_space(3))) unsigned int*)l, 16, 0, 0);
}

// ---------------------------------------------------------------------------
// Kernel 0: cast W -> bf16, rows [K:0-127][Q:128-255][V:256-383], Q pre-scaled
// ---------------------------------------------------------------------------
__global__ __launch_bounds__(256) void castw_kernel(
    const float* __restrict__ Wk, const float* __restrict__ Wq,
    const float* __restrict__ Wv, __bf16* __restrict__ Wb) {
  int idx = blockIdx.x * 256 + threadIdx.x;
  int e   = idx * 4;
  int row = e >> 10;
  int col = e & 1023;
  const float* src;
  float sc = 1.0f;
  if (row < 128) {
    src = Wk + row * DIM_D + col;
  } else if (row < 256) {
    src = Wq + (row - 128) * DIM_D + col;
    sc  = 0.08838834764831845f;  // 1/sqrt(HS) folded into Wq
  } else {
    src = Wv + (row - 256) * DIM_D + col;
  }
  float4 v = *(const float4*)src;
  bf16x4_t o;
  o[0] = (__bf16)(v.x * sc); o[1] = (__bf16)(v.y * sc);
  o[2] = (__bf16)(v.z * sc); o[3] = (__bf16)(v.w * sc);
  *(bf16x4_t*)(Wb + e) = o;
}

// ---------------------------------------------------------------------------
// Kernel 1: projections v6. Block tile 64m x 96n, BK=32, dbuf LDS staging.
// Grid 1024 -> 4 blocks/CU (LDS 28KB). XCD-pinning: the 4 n-siblings of an
// m-stripe get block ids congruent mod 8 -> same XCD -> x fetched once/L2.
// Conflict-free swizzles: As rows 128B -> unit ^ (row&7); Bs rows 64B ->
// unit ^ ((row>>1)&3)  (the old ^(row&3) gave bank-quad 4(row&1)+u = 4-way).
// ---------------------------------------------------------------------------
__global__ __launch_bounds__(256, 4) void proj_kernel(
    const float* __restrict__ x, const __bf16* __restrict__ Wb,
    __bf16* __restrict__ Qb, __bf16* __restrict__ Kb, __bf16* __restrict__ Vt) {
  __shared__ float  As[2][64 * 32];   // 8KB/buf
  __shared__ __bf16 Bs[2][96 * 32];   // 6KB/buf

  const int lane = threadIdx.x & 63;
  const int wave = threadIdx.x >> 6;
  const int lr = lane & 15;
  const int lq = lane >> 4;
  const int wm = wave & 1;   // 32 m-rows
  const int wn = wave >> 1;  // 48 n-cols
  const int bid = blockIdx.x;
  // inverse of: stripe s, sib k -> bid = (s>>3)*32 + 8k + (s&7)
  const int m0 = ((((bid >> 5) << 3) | (bid & 7))) * 64;
  const int n0 = ((bid >> 3) & 3) * 96;

  f32x4_t acc[2][3];
  #pragma unroll
  for (int mt = 0; mt < 2; ++mt)
    #pragma unroll
    for (int nt = 0; nt < 3; ++nt) acc[mt][nt] = (f32x4_t){0.f, 0.f, 0.f, 0.f};

  auto stage = [&](int bufi, int kt) {
    for (int c = wave; c < 14; c += 4) {
      if (c < 8) {             // A: 8 rows x 128B per call
        const int row = c * 8 + (lane >> 3);
        const int u   = (lane & 7) ^ (row & 7);
        async_cp16(x + (size_t)(m0 + row) * DIM_D + kt * 32 + u * 4,
                   &As[bufi][c * 256]);
      } else {                 // B: 16 rows x 64B per call
        const int c2  = c - 8;
        const int row = c2 * 16 + (lane >> 2);
        const int u   = (lane & 3) ^ ((row >> 1) & 3);
        async_cp16(Wb + (size_t)(n0 + row) * DIM_D + kt * 32 + u * 8,
                   &Bs[bufi][c2 * 512]);
      }
    }
  };

  stage(0, 0);
  __syncthreads();

  for (int kt = 0; kt < 32; ++kt) {
    const int cur = kt & 1;
    if (kt + 1 < 32) stage(cur ^ 1, kt + 1);

    bf16x8_t af[2];
    #pragma unroll
    for (int mt = 0; mt < 2; ++mt) {
      const int ml = wm * 32 + mt * 16 + lr;
      const int sw = ml & 7;
      float4 f0 = *(const float4*)(&As[cur][ml * 32 + (((2 * lq)     ^ sw) * 4)]);
      float4 f1 = *(const float4*)(&As[cur][ml * 32 + (((2 * lq + 1) ^ sw) * 4)]);
      bf16x8_t a;
      a[0] = (__bf16)f0.x; a[1] = (__bf16)f0.y;
      a[2] = (__bf16)f0.z; a[3] = (__bf16)f0.w;
      a[4] = (__bf16)f1.x; a[5] = (__bf16)f1.y;
      a[6] = (__bf16)f1.z; a[7] = (__bf16)f1.w;
      af[mt] = a;
    }
    bf16x8_t bfv[3];
    #pragma unroll
    for (int nt = 0; nt < 3; ++nt) {
      const int nl = wn * 48 + nt * 16 + lr;
      bfv[nt] = *(const bf16x8_t*)(&Bs[cur][nl * 32 + ((lq ^ ((nl >> 1) & 3)) * 8)]);
    }
    #pragma unroll
    for (int mt = 0; mt < 2; ++mt)
      #pragma unroll
      for (int nt = 0; nt < 3; ++nt)
        acc[mt][nt] = mfma_16x16x32(af[mt], bfv[nt], acc[mt][nt]);
    __syncthreads();
  }

  #pragma unroll
  for (int mt = 0; mt < 2; ++mt) {
    const int t0 = m0 + wm * 32 + mt * 16 + lq * 4;
    #pragma unroll
    for (int nt = 0; nt < 3; ++nt) {
      const int nn = n0 + wn * 48 + nt * 16 + lr;
      if (nn < 256) {
        __bf16* dst = (nn < 128) ? (Kb + nn) : (Qb + (nn - 128));
        #pragma unroll
        for (int r = 0; r < 4; ++r)
          dst[(size_t)(t0 + r) * HS_N] = (__bf16)acc[mt][nt][r];
      } else {
        const int bb = t0 >> 11;
        const int tl = t0 & 2047;
        bf16x4_t o;
        #pragma unroll
        for (int r = 0; r < 4; ++r) o[r] = (__bf16)acc[mt][nt][r];
        *(bf16x4_t*)(Vt + (size_t)bb * (HS_N * SEQ_T) + (size_t)(nn - 256) * SEQ_T + tl) = o;
      }
    }
  }
}

// ---------------------------------------------------------------------------
// Kernel 1b: per-batch max ||k||^2 (for the softmax upper bound).
// 16384 keys; wave-reduce then one atomicMax per wave (non-neg float as uint).
// ---------------------------------------------------------------------------
__global__ __launch_bounds__(256) void knorm_kernel(
    const __bf16* __restrict__ Kb, unsigned int* __restrict__ km) {
  const int t = blockIdx.x * 256 + threadIdx.x;   // 0..16383; block within one batch
  const __bf16* kp = Kb + (size_t)t * HS_N;
  float ss = 0.f;
  #pragma unroll
  for (int i = 0; i < 16; ++i) {
    bf16x8_t v = *(const bf16x8_t*)(kp + i * 8);
    #pragma unroll
    for (int j = 0; j < 8; ++j) { float f = (float)v[j]; ss += f * f; }
  }
  #pragma unroll
  for (int off = 1; off < 64; off <<= 1) ss = fmaxf(ss, __shfl_xor(ss, off));
  if ((threadIdx.x & 63) == 0) atomicMax(km + (t >> 11), __float_as_uint(ss));
}

// ---------------------------------------------------------------------------
// Kernel 2: flash attention v5 — bounded-max softmax.
// m_row = ||q_hat_row|| * max_j ||k_j|| >= any score (Cauchy-Schwarz), fixed
// up front -> no per-chunk max/alpha/rescale chain. Chunk = QK -> exp ->
// P-LDS -> PV. Block = 2 waves (16 q-rows each, no merge); K/V 64-key chunks
// double-buffered via global_load_lds; heavy+light block pairing.
// ---------------------------------------------------------------------------
__global__ __launch_bounds__(128) void attn_kernel(
    const __bf16* __restrict__ Qb, const __bf16* __restrict__ Kb,
    const __bf16* __restrict__ Vt, const unsigned int* __restrict__ km,
    float* __restrict__ out) {
  __shared__ __bf16 Ks[2][64 * 128];   // 16KB/buf; 256B rows, swz ^(row&15)
  __shared__ __bf16 Vs[2][128 * 64];   // 16KB/buf; 128B rows, swz ^(row&7)
  __shared__ __bf16 pbuf[2][16 * 72];  // per-wave P C/D->A round-trip

  const int lane = threadIdx.x & 63;
  const int wave = threadIdx.x >> 6;       // 0..1
  const int lr = lane & 15;
  const int lq = lane >> 4;
  const int b  = blockIdx.x & 7;           // batch pinned to XCD (b == bid mod 8)
  const int r  = blockIdx.x >> 3;                    // 0..63
  const int jg = (r < 32) ? (63 - r) : (r - 32);     // heavy first + pairing
  const int q0 = jg * 32 + wave * 16;
  const int C  = (jg * 32 + 95) >> 6;                // 64-key chunks

  const __bf16* Qbb = Qb + (size_t)b * (SEQ_T * HS_N);
  const __bf16* Kbb = Kb + (size_t)b * (SEQ_T * HS_N);
  const __bf16* Vbb = Vt + (size_t)b * (HS_N * SEQ_T);
  float* ob = out + (size_t)b * (SEQ_T * HS_N);
  __bf16* pb = pbuf[wave];

  bf16x8_t qf[4];
  #pragma unroll
  for (int ks = 0; ks < 4; ++ks)
    qf[ks] = *(const bf16x8_t*)(Qbb + (size_t)(q0 + lr) * HS_N + ks * 32 + lq * 8);

  // ---- fixed per-row softmax bound: m = ||q_hat_row|| * max||k|| ----
  const float km2 = __uint_as_float(km[b]);
  float qn2 = 0.f;
  #pragma unroll
  for (int ks = 0; ks < 4; ++ks)
    #pragma unroll
    for (int j = 0; j < 8; ++j) { float f = (float)qf[ks][j]; qn2 += f * f; }
  qn2 += __shfl_xor(qn2, 16);
  qn2 += __shfl_xor(qn2, 32);        // lanes now hold full ||q_hat_{row=lr}||^2
  float mrow[4];
  #pragma unroll
  for (int r2 = 0; r2 < 4; ++r2)
    mrow[r2] = sqrtf(__shfl(qn2, (lane >> 4) * 4 + r2) * km2);

  f32x4_t Oa[8];
  #pragma unroll
  for (int o = 0; o < 8; ++o) Oa[o] = (f32x4_t){0.f, 0.f, 0.f, 0.f};
  float lsum[4] = {0.f, 0.f, 0.f, 0.f};

  auto stage = [&](int bufi, int c) {
    const int kk = c * 64;
    if (wave == 0) {                 // K: 64 rows x 256B
      #pragma unroll
      for (int i = 0; i < 16; ++i) {
        const int row = i * 4 + (lane >> 4);
        const int u   = (lane & 15) ^ (row & 15);
        async_cp16(Kbb + (size_t)(kk + row) * HS_N + u * 8, &Ks[bufi][i * 512]);
      }
    } else {                         // V: 128 rows x 128B (rows are HS dims)
      #pragma unroll
      for (int i = 0; i < 16; ++i) {
        const int row = i * 8 + (lane >> 3);
        const int u   = (lane & 7) ^ (row & 7);
        async_cp16(Vbb + (size_t)row * SEQ_T + kk + u * 8, &Vs[bufi][i * 512]);
      }
    }
  };

  stage(0, 0);
  __syncthreads();

  for (int c = 0; c < C; ++c) {
    const int cur = c & 1;
    if (c + 1 < C) stage(cur ^ 1, c + 1);
    const int kk = c * 64;

    // ---- QK^T from LDS (scale folded into Q) ----
    f32x4_t s[4];
    #pragma unroll
    for (int nt = 0; nt < 4; ++nt) s[nt] = (f32x4_t){0.f, 0.f, 0.f, 0.f};
    #pragma unroll
    for (int ks = 0; ks < 4; ++ks)
      #pragma unroll
      for (int nt = 0; nt < 4; ++nt) {
        bf16x8_t kf = *(const bf16x8_t*)(
            &Ks[cur][(nt * 16 + lr) * 128 + (((ks * 4 + lq) ^ lr) * 8)]);
        s[nt] = mfma_16x16x32(qf[ks], kf, s[nt]);
      }
    if (kk + 63 > q0) {  // mask whenever chunk max col can exceed tile min row
      #pragma unroll
      for (int nt = 0; nt < 4; ++nt) {
        const int col = kk + nt * 16 + lr;
        #pragma unroll
        for (int r2 = 0; r2 < 4; ++r2)
          if (col > q0 + lq * 4 + r2) s[nt][r2] = -INFINITY;
      }
    }

    // ---- exp against the fixed bound; no max update, no rescale ----
    #pragma unroll
    for (int r2 = 0; r2 < 4; ++r2) {
      float p0 = __expf(s[0][r2] - mrow[r2]);
      float p1 = __expf(s[1][r2] - mrow[r2]);
      float p2 = __expf(s[2][r2] - mrow[r2]);
      float p3 = __expf(s[3][r2] - mrow[r2]);
      s[0][r2] = p0; s[1][r2] = p1; s[2][r2] = p2; s[3][r2] = p3;
      lsum[r2] += (p0 + p1) + (p2 + p3);
    }

    // ---- P: C/D -> LDS -> A layout; PV from LDS ----
    #pragma unroll
    for (int nt = 0; nt < 4; ++nt)
      #pragma unroll
      for (int r2 = 0; r2 < 4; ++r2)
        pb[(lq * 4 + r2) * 72 + nt * 16 + lr] = (__bf16)s[nt][r2];

    #pragma unroll
    for (int k2 = 0; k2 < 2; ++k2) {
      bf16x8_t afr = *(const bf16x8_t*)(pb + lr * 72 + k2 * 32 + lq * 8);
      #pragma unroll
      for (int o = 0; o < 8; ++o) {
        bf16x8_t vfr = *(const bf16x8_t*)(
            &Vs[cur][(o * 16 + lr) * 64 + (((k2 * 4 + lq) ^ (lr & 7)) * 8)]);
        Oa[o] = mfma_16x16x32(afr, vfr, Oa[o]);
      }
    }
    __syncthreads();   // drains stage(c+1); protects buffer reuse
  }

  // ---- l reduction + normalize + store ----
  #pragma unroll
  for (int r2 = 0; r2 < 4; ++r2) {
    float v = lsum[r2];
    v += __shfl_xor(v, 1);
    v += __shfl_xor(v, 2);
    v += __shfl_xor(v, 4);
    v += __shfl_xor(v, 8);
    const float inv = 1.0f / v;
    const int rowg = q0 + lq * 4 + r2;
    #pragma unroll
    for (int o = 0; o < 8; ++o)
      ob[(size_t)rowg * HS_N + o * 16 + lr] = Oa[o][r2] * inv;
  }
}

// ---------------------------------------------------------------------------
extern "C" void kernel_launch(void* const* d_in, const int* in_sizes, int n_in,
                              void* d_out, int out_size, void* d_ws, size_t ws_size,
                              hipStream_t stream) {
  const float* x  = (const float*)d_in[0];
  const float* Wk = (const float*)d_in[1];
  const float* Wq = (const float*)d_in[2];
  const float* Wv = (const float*)d_in[3];
  float* out = (float*)d_out;

  char* ws = (char*)d_ws;
  __bf16* Wb = (__bf16*)ws;                          //   786432 B
  __bf16* Qb = (__bf16*)(ws + 786432);               //  4194304 B
  __bf16* Kb = (__bf16*)(ws + 786432 + 4194304);     //  4194304 B
  __bf16* Vt = (__bf16*)(ws + 786432 + 8388608);     //  4194304 B
  unsigned int* km = (unsigned int*)(ws + 786432 + 12582912);  // 32 B

  castw_kernel<<<384, 256, 0, stream>>>(Wk, Wq, Wv, Wb);
  proj_kernel<<<1024, 256, 0, stream>>>(x, Wb, Qb, Kb, Vt);
  hipMemsetAsync(km, 0, 8 * sizeof(unsigned int), stream);
  knorm_kernel<<<64, 256, 0, stream>>>(Kb, km);
  attn_kernel<<<512, 128, 0, stream>>>(Qb, Kb, Vt, km, out);
}